// Round 11
// baseline (118.086 us; speedup 1.0000x reference)
//
#include <hip/hip_runtime.h>

typedef __attribute__((ext_vector_type(2))) __fp16 h2;
typedef __attribute__((ext_vector_type(4))) __fp16 h4;
typedef __attribute__((ext_vector_type(8))) __fp16 h8;
typedef __attribute__((ext_vector_type(4))) float f32x4;

#define LOG2E 1.44269504088896340736f

// ws layout (bytes) — identical to rounds 6/7 (verified passing)
#define WS_K    0ull            // 14*64 tiles * 8192 B
#define WS_MK   7340032ull      // 14*16 tiles * 8192 B
#define WS_VT   9175040ull      // 14*64 tiles * 512 B
#define WS_MVT  9633792ull      // 14*16 tiles * 512 B
#define WS_NEED 9748480ull

__device__ __forceinline__ h2 pkrtz(float a, float b) {
    return __builtin_bit_cast(h2, __builtin_amdgcn_cvt_pkrtz(a, b));
}

__device__ __forceinline__ void gll16(const void* g, void* l) {
    __builtin_amdgcn_global_load_lds(
        (const __attribute__((address_space(1))) unsigned int*)g,
        (__attribute__((address_space(3))) unsigned int*)l, 16, 0, 0);
}

// ---------------- Precompute (verbatim round 6/7, verified) ----------------
__global__ __launch_bounds__(256) void kast_pre_kernel(
    const float* __restrict__ K, const float* __restrict__ V,
    const float* __restrict__ MK, const float* __restrict__ MV,
    char* __restrict__ ws)
{
    const int id = blockIdx.x * 256 + threadIdx.x;
    if (id < 573440) {
        const bool ismk = id >= 458752;
        const int lid = ismk ? id - 458752 : id;
        const int c = lid & 7;
        const int r = (lid >> 3) & 63;
        int kt, s;
        if (ismk) { kt = (lid >> 9) & 15; s = lid >> 13; }
        else      { kt = (lid >> 9) & 63; s = lid >> 15; }
        const int b = s / 7, t = s - b * 7;
        const float* src = ismk
            ? MK + (((size_t)(b * 7 + t) * 1024 + kt * 64 + r) * 64 + c * 8)
            : K  + (((size_t)(b * 8 + t) * 4096 + kt * 64 + r) * 64 + c * 8);
        const f32x4 xa = *(const f32x4*)src;
        const f32x4 xb = *(const f32x4*)(src + 4);
        const h2 q0 = pkrtz(xa[0], xa[1]), q1 = pkrtz(xa[2], xa[3]);
        const h2 q2 = pkrtz(xb[0], xb[1]), q3 = pkrtz(xb[2], xb[3]);
        const h8 out = {q0[0], q0[1], q1[0], q1[1], q2[0], q2[1], q3[0], q3[1]};
        __fp16* dst = (__fp16*)(ws + (ismk ? WS_MK : WS_K))
                    + (size_t)(ismk ? (s * 16 + kt) : (s * 64 + kt)) * 4096
                    + r * 64 + ((c ^ (r & 7)) * 8);
        *(h8*)dst = out;
    } else {
        const int vid = id - 573440;
        const bool ismv = vid >= 57344;
        const int lid = ismv ? vid - 57344 : vid;
        const int c = lid & 15;
        const int d = (lid >> 4) & 3;
        int kt, s;
        if (ismv) { kt = (lid >> 6) & 15; s = lid >> 10; }
        else      { kt = (lid >> 6) & 63; s = lid >> 12; }
        const int b = s / 7, t = s - b * 7;
        const float* src = ismv
            ? MV + (((size_t)(b * 7 + t) * 1024 + kt * 64 + c * 4) * 3)
            : V  + (((size_t)(b * 8 + t) * 4096 + kt * 64 + c * 4) * 3);
        float f0, f1, f2, f3;
        if (d == 3) { f0 = f1 = f2 = f3 = 1.0f; }
        else { f0 = src[d]; f1 = src[3 + d]; f2 = src[6 + d]; f3 = src[9 + d]; }
        const h2 pa = pkrtz(f0, f1), pb = pkrtz(f2, f3);
        const h4 out4 = {pa[0], pa[1], pb[0], pb[1]};
        __fp16* dst = (__fp16*)(ws + (ismv ? WS_MVT : WS_VT))
                    + (size_t)(ismv ? (s * 16 + kt) : (s * 64 + kt)) * 256
                    + d * 64 + (4 * ((c >> 2) ^ d) + (c & 3)) * 4;
        *(h4*)dst = out4;
    }
}

// -------- Main: round-10 structure + PER-QUERY softmax max (the r9/r10 fix) --------
__global__ __launch_bounds__(512) void kast_attn_kernel(
    const float* __restrict__ K,   // (2,8,4096,64) for Q
    const char* __restrict__ ws,
    float* __restrict__ OUT)       // (2,7,4096,3)
{
    __shared__ alignas(16) __fp16 sK2[2][2][64][64];   // [half][buf]
    __shared__ alignas(16) __fp16 sVT2[2][2][4][64];   // [half][buf]
    __shared__ float mrg[8][32][5];                    // [wave][q32][{m,O0,O1,O2,l}]

    const int id = blockIdx.x;
    const int sw = (id & 7) * 112 + (id >> 3);   // XCD-chunked, bijective (896%8==0)
    const int bt = sw >> 6;
    const int qblk = sw & 63;
    const int b = bt / 7, t = bt - b * 7;

    const int tid = threadIdx.x;
    const int lane = tid & 63;
    const int w = tid >> 6;      // wave 0..7
    const int h = w >> 2;        // key-half 0/1
    const int wl = w & 3;        // wave within half
    const int qsub = wl >> 1;    // query 32-subset 0/1
    const int ntp = wl & 1;      // nt-pair subset 0/1 (keys [ntp*32, ntp*32+32) of tile)
    const int col = lane & 15;   // q within M-tile
    const int g = lane >> 4;     // k-chunk group
    const int cs = col & 7;      // K-read swizzle key
    const int d3 = col & 3;      // V^T row

    // ---- Q fragments (B operand), 2 M-tiles, scaled by log2(e) ----
    h8 aq[2][2];                 // [mt][ch]
#pragma unroll
    for (int mt = 0; mt < 2; ++mt) {
        const float* qp = K + (((size_t)b * 8 + (t + 1)) * 4096
                         + (size_t)(qblk * 64 + qsub * 32 + mt * 16 + col)) * 64;
#pragma unroll
        for (int ch = 0; ch < 2; ++ch) {
            const int cc = ch * 32 + g * 8;
            const f32x4 xa = *(const f32x4*)&qp[cc];
            const f32x4 xb = *(const f32x4*)&qp[cc + 4];
            const h2 p0 = pkrtz(xa[0] * LOG2E, xa[1] * LOG2E);
            const h2 p1 = pkrtz(xa[2] * LOG2E, xa[3] * LOG2E);
            const h2 p2 = pkrtz(xb[0] * LOG2E, xb[1] * LOG2E);
            const h2 p3 = pkrtz(xb[2] * LOG2E, xb[3] * LOG2E);
            aq[mt][ch] = (h8){p0[0], p0[1], p1[0], p1[1], p2[0], p2[1], p3[0], p3[1]};
        }
    }

    auto stage = [&](const char* kb, const char* vb, int tkt, int buf) {
        const char* ksrc = kb + (size_t)tkt * 8192 + wl * 2048 + lane * 16;
        char* kdst = ((char*)&sK2[h][buf][0][0]) + wl * 2048 + lane * 16;
        gll16(ksrc, kdst);
        gll16(ksrc + 1024, kdst + 1024);
        if (wl == 0 && lane < 32)
            ((f32x4*)&sVT2[h][buf][0][0])[lane] =
                ((const f32x4*)(vb + (size_t)tkt * 512))[lane];
    };

    float oa0 = 0.f, oa1 = 0.f, oa2 = 0.f;   // merge accumulators (tid<64)

#pragma unroll
    for (int phase = 0; phase < 2; ++phase) {
        const char* kbase; const char* vbase; int ntile; float wgt;
        if (phase == 0) {
            ntile = 32; wgt = 0.8f;
            kbase = ws + WS_K  + ((size_t)bt * 64 + h * 32) * 8192;
            vbase = ws + WS_VT + ((size_t)bt * 64 + h * 32) * 512;
        } else {
            ntile = 8; wgt = 0.2f;
            kbase = ws + WS_MK  + ((size_t)bt * 16 + h * 8) * 8192;
            vbase = ws + WS_MVT + ((size_t)bt * 16 + h * 8) * 512;
        }

        // prologue: tile 0 -> buf 0
        stage(kbase, vbase, 0, 0);
        __syncthreads();

        float mrun[2] = {-1e30f, -1e30f};
        f32x4 O[2] = {(f32x4){0.f,0.f,0.f,0.f}, (f32x4){0.f,0.f,0.f,0.f}};

        for (int kt = 0; kt < ntile; ++kt) {
            const int cur = kt & 1;

            // issue next tile's staging early; end-of-iter __syncthreads drains it
            if (kt + 1 < ntile) stage(kbase, vbase, kt + 1, cur ^ 1);

            // ---- QK^T (swapped: A=K frag, B=Q frag); this wave: 32k x 32q ----
            f32x4 acc[2][2];   // [mt][nt-local]
#pragma unroll
            for (int mt = 0; mt < 2; ++mt)
#pragma unroll
                for (int nt = 0; nt < 2; ++nt) acc[mt][nt] = (f32x4){0.f,0.f,0.f,0.f};
            __builtin_amdgcn_s_setprio(1);
#pragma unroll
            for (int ch = 0; ch < 2; ++ch) {
                h8 bh[2];
#pragma unroll
                for (int nt = 0; nt < 2; ++nt) {
                    const int nt2 = ntp * 2 + nt;
                    bh[nt] = *(const h8*)&sK2[h][cur][nt2 * 16 + col][((ch * 4 + g) ^ cs) * 8];
                }
#pragma unroll
                for (int mt = 0; mt < 2; ++mt)
#pragma unroll
                    for (int nt = 0; nt < 2; ++nt)
                        acc[mt][nt] = __builtin_amdgcn_mfma_f32_16x16x32_f16(bh[nt], aq[mt][ch], acc[mt][nt], 0, 0, 0);
            }
            __builtin_amdgcn_s_setprio(0);
            // lane holds S[key = (ntp*2+nt)*16 + 4g + j][q = qsub*32 + mt*16 + col]

            // ---- online softmax + PV, PER M-TILE (per-query max: r9/r10 fix) ----
            const char* vtb = (const char*)&sVT2[h][cur][0][0] + d3 * 128;
#pragma unroll
            for (int mt = 0; mt < 2; ++mt) {
                float tm = acc[mt][0][0];
#pragma unroll
                for (int nt = 0; nt < 2; ++nt)
#pragma unroll
                    for (int j = 0; j < 4; ++j) tm = fmaxf(tm, acc[mt][nt][j]);
                tm = fmaxf(tm, __shfl_xor(tm, 16));
                tm = fmaxf(tm, __shfl_xor(tm, 32));
                if (!__all(tm <= mrun[mt])) {
                    const float mnew = fmaxf(mrun[mt], tm);
                    const float sc = __builtin_amdgcn_exp2f(mrun[mt] - mnew);
                    O[mt] *= sc;
                    mrun[mt] = mnew;
                }
#pragma unroll
                for (int nt = 0; nt < 2; ++nt) {
                    const int nt2 = ntp * 2 + nt;
                    const float p0 = __builtin_amdgcn_exp2f(acc[mt][nt][0] - mrun[mt]);
                    const float p1 = __builtin_amdgcn_exp2f(acc[mt][nt][1] - mrun[mt]);
                    const float p2 = __builtin_amdgcn_exp2f(acc[mt][nt][2] - mrun[mt]);
                    const float p3 = __builtin_amdgcn_exp2f(acc[mt][nt][3] - mrun[mt]);
                    const h2 pa = pkrtz(p0, p1), pb = pkrtz(p2, p3);
                    const h4 pf = (h4){pa[0], pa[1], pb[0], pb[1]};
                    const h4 vf = *(const h4*)(vtb + (4 * (nt2 ^ d3) + g) * 8);
                    O[mt] = __builtin_amdgcn_mfma_f32_16x16x16f16(vf, pf, O[mt], 0, 0, 0);
                }
            }

            __syncthreads();   // drains staged tile kt+1; safe buffer swap
        }

        // ---- partials to LDS; exact 4-way flash merge for this phase ----
        if (g == 0) {
#pragma unroll
            for (int mt = 0; mt < 2; ++mt) {
                float* m5 = &mrg[w][mt * 16 + col][0];
                m5[0] = mrun[mt];
                m5[1] = O[mt][0]; m5[2] = O[mt][1]; m5[3] = O[mt][2]; m5[4] = O[mt][3];
            }
        }
        __syncthreads();
        if (tid < 64) {
            const int qh = tid >> 5, ql = tid & 31;
            // contributing waves for query qh*32+ql: w = h*4 + qh*2 + ntp
            float m = -1e30f;
#pragma unroll
            for (int c = 0; c < 4; ++c) {
                const int w4 = (c >> 1) * 4 + qh * 2 + (c & 1);
                m = fmaxf(m, mrg[w4][ql][0]);
            }
            float l = 0.f, r0 = 0.f, r1 = 0.f, r2 = 0.f;
#pragma unroll
            for (int c = 0; c < 4; ++c) {
                const int w4 = (c >> 1) * 4 + qh * 2 + (c & 1);
                const float* m5 = &mrg[w4][ql][0];
                const float e = __builtin_amdgcn_exp2f(m5[0] - m);
                r0 += m5[1] * e; r1 += m5[2] * e; r2 += m5[3] * e;
                l  += m5[4] * e;
            }
            const float inv = wgt / l;
            oa0 += r0 * inv; oa1 += r1 * inv; oa2 += r2 * inv;
        }
        // next phase's prologue barrier orders mrg reuse
    }

    if (tid < 64) {
        const int q = qblk * 64 + tid;
        float* op = OUT + (((size_t)b * 7 + t) * 4096 + (size_t)q) * 3;
        op[0] = oa0; op[1] = oa1; op[2] = oa2;
    }
}

// ---------------- Fallback (round-4 kernel, known-good) if ws too small ----------------
__global__ __launch_bounds__(256) void kast_attn_fb(
    const float* __restrict__ K, const float* __restrict__ V,
    const float* __restrict__ MK, const float* __restrict__ MV,
    float* __restrict__ OUT)
{
    __shared__ alignas(16) __fp16 sK[2][64][64];
    __shared__ alignas(16) __fp16 sVT[2][4][68];

    const int id = blockIdx.x;
    const int sw = (id & 7) * 112 + (id >> 3);
    const int bt = sw >> 6;
    const int qblk = sw & 63;
    const int b = bt / 7, t = bt % 7;

    const int tid = threadIdx.x;
    const int lane = tid & 63;
    const int w = tid >> 6;
    const int col = lane & 15;
    const int g = lane >> 4;

    const int r = tid >> 2;
    const int c0 = (tid & 3) * 16;
    const int rs = (r & 7) << 3;
    const unsigned vr = (unsigned)tid / 3u;
    const unsigned vd = (unsigned)tid - vr * 3u;

    if (tid < 128) sVT[tid >> 6][3][tid & 63] = (__fp16)1.0f;

    const float* Qbase = K + (((size_t)b * 8 + (t + 1)) * 4096) * 64;
    h8 aq[2];
    {
        const int qrow = qblk * 64 + w * 16 + col;
        const float* qp = Qbase + (size_t)qrow * 64;
#pragma unroll
        for (int ch = 0; ch < 2; ++ch) {
            const int cc = ch * 32 + g * 8;
            const f32x4 xa = *(const f32x4*)&qp[cc];
            const f32x4 xb = *(const f32x4*)&qp[cc + 4];
            const h2 p0 = pkrtz(xa[0] * LOG2E, xa[1] * LOG2E);
            const h2 p1 = pkrtz(xa[2] * LOG2E, xa[3] * LOG2E);
            const h2 p2 = pkrtz(xb[0] * LOG2E, xb[1] * LOG2E);
            const h2 p3 = pkrtz(xb[2] * LOG2E, xb[3] * LOG2E);
            aq[ch] = (h8){p0[0], p0[1], p1[0], p1[1], p2[0], p2[1], p3[0], p3[1]};
        }
    }

    float outc0 = 0.f, outc1 = 0.f, outc2 = 0.f;

    for (int phase = 0; phase < 2; ++phase) {
        const float* kp; const float* vp; int ntile; float wgt;
        if (phase == 0) {
            kp = K + (((size_t)b * 8 + t) * 4096) * 64;
            vp = V + (((size_t)b * 8 + t) * 4096) * 3;
            ntile = 64; wgt = 0.8f;
        } else {
            kp = MK + (((size_t)b * 7 + t) * 1024) * 64;
            vp = MV + (((size_t)b * 7 + t) * 1024) * 3;
            ntile = 16; wgt = 0.2f;
        }
        {
            const float* src = kp + ((size_t)r) * 64 + c0;
            const f32x4* s4 = (const f32x4*)src;
            const f32x4 ra = s4[0], rb = s4[1], rc = s4[2], rd = s4[3];
            const h2 q0 = pkrtz(ra[0], ra[1]), q1 = pkrtz(ra[2], ra[3]);
            const h2 q2 = pkrtz(rb[0], rb[1]), q3 = pkrtz(rb[2], rb[3]);
            const h2 q4 = pkrtz(rc[0], rc[1]), q5 = pkrtz(rc[2], rc[3]);
            const h2 q6 = pkrtz(rd[0], rd[1]), q7 = pkrtz(rd[2], rd[3]);
            *(h8*)&sK[0][r][c0 ^ rs] = (h8){q0[0], q0[1], q1[0], q1[1], q2[0], q2[1], q3[0], q3[1]};
            *(h8*)&sK[0][r][(c0 + 8) ^ rs] = (h8){q4[0], q4[1], q5[0], q5[1], q6[0], q6[1], q7[0], q7[1]};
            if (tid < 192) sVT[0][vd][vr] = (__fp16)vp[tid];
        }
        __syncthreads();

        float mrun = -1e30f;
        f32x4 O = (f32x4){0.f, 0.f, 0.f, 0.f};

        for (int kt = 0; kt < ntile; ++kt) {
            const int cur = kt & 1;
            const bool have = (kt + 1) < ntile;
            f32x4 ra, rb, rc, rd; float rv = 0.f;
            if (have) {
                const float* src = kp + ((size_t)(kt + 1) * 64 + r) * 64 + c0;
                const f32x4* s4 = (const f32x4*)src;
                ra = s4[0]; rb = s4[1]; rc = s4[2]; rd = s4[3];
                if (tid < 192) rv = vp[(size_t)(kt + 1) * 192 + tid];
            }
            f32x4 acc[4];
#pragma unroll
            for (int nt = 0; nt < 4; ++nt) acc[nt] = (f32x4){0.f, 0.f, 0.f, 0.f};
#pragma unroll
            for (int ch = 0; ch < 2; ++ch) {
                h8 bh[4];
#pragma unroll
                for (int nt = 0; nt < 4; ++nt) {
                    const int rr = nt * 16 + col;
                    const int cc = (ch * 32 + g * 8) ^ ((rr & 7) << 3);
                    bh[nt] = *(const h8*)&sK[cur][rr][cc];
                }
#pragma unroll
                for (int nt = 0; nt < 4; ++nt)
                    acc[nt] = __builtin_amdgcn_mfma_f32_16x16x32_f16(bh[nt], aq[ch], acc[nt], 0, 0, 0);
            }
            {
                float tm = acc[0][0];
#pragma unroll
                for (int nt = 0; nt < 4; ++nt)
#pragma unroll
                    for (int j = 0; j < 4; ++j) tm = fmaxf(tm, acc[nt][j]);
                tm = fmaxf(tm, __shfl_xor(tm, 16));
                tm = fmaxf(tm, __shfl_xor(tm, 32));
                if (!__all(tm <= mrun)) {
                    const float mnew = fmaxf(mrun, tm);
                    const float sc = __builtin_amdgcn_exp2f(mrun - mnew);
                    O *= sc;
                    mrun = mnew;
                }
            }
#pragma unroll
            for (int nt = 0; nt < 4; ++nt) {
                const float p0 = __builtin_amdgcn_exp2f(acc[nt][0] - mrun);
                const float p1 = __builtin_amdgcn_exp2f(acc[nt][1] - mrun);
                const float p2 = __builtin_amdgcn_exp2f(acc[nt][2] - mrun);
                const float p3 = __builtin_amdgcn_exp2f(acc[nt][3] - mrun);
                const h2 pa = pkrtz(p0, p1), pb = pkrtz(p2, p3);
                const h4 pf = (h4){pa[0], pa[1], pb[0], pb[1]};
                const h4 vf = *(const h4*)&sVT[cur][col & 3][nt * 16 + 4 * g];
                O = __builtin_amdgcn_mfma_f32_16x16x16f16(vf, pf, O, 0, 0, 0);
            }
            if (have) {
                const int nb = cur ^ 1;
                const h2 q0 = pkrtz(ra[0], ra[1]), q1 = pkrtz(ra[2], ra[3]);
                const h2 q2 = pkrtz(rb[0], rb[1]), q3 = pkrtz(rb[2], rb[3]);
                const h2 q4 = pkrtz(rc[0], rc[1]), q5 = pkrtz(rc[2], rc[3]);
                const h2 q6 = pkrtz(rd[0], rd[1]), q7 = pkrtz(rd[2], rd[3]);
                *(h8*)&sK[nb][r][c0 ^ rs] = (h8){q0[0], q0[1], q1[0], q1[1], q2[0], q2[1], q3[0], q3[1]};
                *(h8*)&sK[nb][r][(c0 + 8) ^ rs] = (h8){q4[0], q4[1], q5[0], q5[1], q6[0], q6[1], q7[0], q7[1]};
                if (tid < 192) sVT[nb][vd][vr] = (__fp16)rv;
            }
            __syncthreads();
        }
        const float inv = wgt / O[3];
        outc0 += O[0] * inv;
        outc1 += O[1] * inv;
        outc2 += O[2] * inv;
    }

    if (g == 0) {
        const int q = qblk * 64 + w * 16 + col;
        float* op = OUT + (((size_t)b * 7 + t) * 4096 + (size_t)q) * 3;
        op[0] = outc0; op[1] = outc1; op[2] = outc2;
    }
}

extern "C" void kernel_launch(void* const* d_in, const int* in_sizes, int n_in,
                              void* d_out, int out_size, void* d_ws, size_t ws_size,
                              hipStream_t stream) {
    const float* K  = (const float*)d_in[0];
    const float* V  = (const float*)d_in[1];
    const float* MK = (const float*)d_in[2];
    const float* MV = (const float*)d_in[3];
    float* OUT = (float*)d_out;
    if (ws_size >= WS_NEED) {
        hipLaunchKernelGGL(kast_pre_kernel, dim3(2520), dim3(256), 0, stream,
                           K, V, MK, MV, (char*)d_ws);
        hipLaunchKernelGGL(kast_attn_kernel, dim3(896), dim3(512), 0, stream,
                           K, (const char*)d_ws, OUT);
    } else {
        hipLaunchKernelGGL(kast_attn_fb, dim3(896), dim3(256), 0, stream,
                           K, V, MK, MV, OUT);
    }
}

// Round 12
// 104.364 us; speedup vs baseline: 1.1315x; 1.1315x over previous
//
#include <hip/hip_runtime.h>

typedef __attribute__((ext_vector_type(2))) __fp16 h2;
typedef __attribute__((ext_vector_type(4))) __fp16 h4;
typedef __attribute__((ext_vector_type(8))) __fp16 h8;
typedef __attribute__((ext_vector_type(4))) float f32x4;

#define LOG2E 1.44269504088896340736f

// ws layout (bytes) — identical to rounds 6/7/11 (verified passing)
#define WS_K    0ull            // 14*64 tiles * 8192 B
#define WS_MK   7340032ull      // 14*16 tiles * 8192 B
#define WS_VT   9175040ull      // 14*64 tiles * 512 B
#define WS_MVT  9633792ull      // 14*16 tiles * 512 B
#define WS_NEED 9748480ull

__device__ __forceinline__ h2 pkrtz(float a, float b) {
    return __builtin_bit_cast(h2, __builtin_amdgcn_cvt_pkrtz(a, b));
}

__device__ __forceinline__ void gll16(const void* g, void* l) {
    __builtin_amdgcn_global_load_lds(
        (const __attribute__((address_space(1))) unsigned int*)g,
        (__attribute__((address_space(3))) unsigned int*)l, 16, 0, 0);
}

// ---------------- Precompute (verbatim round 6/7/11, verified) ----------------
__global__ __launch_bounds__(256) void kast_pre_kernel(
    const float* __restrict__ K, const float* __restrict__ V,
    const float* __restrict__ MK, const float* __restrict__ MV,
    char* __restrict__ ws)
{
    const int id = blockIdx.x * 256 + threadIdx.x;
    if (id < 573440) {
        const bool ismk = id >= 458752;
        const int lid = ismk ? id - 458752 : id;
        const int c = lid & 7;
        const int r = (lid >> 3) & 63;
        int kt, s;
        if (ismk) { kt = (lid >> 9) & 15; s = lid >> 13; }
        else      { kt = (lid >> 9) & 63; s = lid >> 15; }
        const int b = s / 7, t = s - b * 7;
        const float* src = ismk
            ? MK + (((size_t)(b * 7 + t) * 1024 + kt * 64 + r) * 64 + c * 8)
            : K  + (((size_t)(b * 8 + t) * 4096 + kt * 64 + r) * 64 + c * 8);
        const f32x4 xa = *(const f32x4*)src;
        const f32x4 xb = *(const f32x4*)(src + 4);
        const h2 q0 = pkrtz(xa[0], xa[1]), q1 = pkrtz(xa[2], xa[3]);
        const h2 q2 = pkrtz(xb[0], xb[1]), q3 = pkrtz(xb[2], xb[3]);
        const h8 out = {q0[0], q0[1], q1[0], q1[1], q2[0], q2[1], q3[0], q3[1]};
        __fp16* dst = (__fp16*)(ws + (ismk ? WS_MK : WS_K))
                    + (size_t)(ismk ? (s * 16 + kt) : (s * 64 + kt)) * 4096
                    + r * 64 + ((c ^ (r & 7)) * 8);
        *(h8*)dst = out;
    } else {
        const int vid = id - 573440;
        const bool ismv = vid >= 57344;
        const int lid = ismv ? vid - 57344 : vid;
        const int c = lid & 15;
        const int d = (lid >> 4) & 3;
        int kt, s;
        if (ismv) { kt = (lid >> 6) & 15; s = lid >> 10; }
        else      { kt = (lid >> 6) & 63; s = lid >> 12; }
        const int b = s / 7, t = s - b * 7;
        const float* src = ismv
            ? MV + (((size_t)(b * 7 + t) * 1024 + kt * 64 + c * 4) * 3)
            : V  + (((size_t)(b * 8 + t) * 4096 + kt * 64 + c * 4) * 3);
        float f0, f1, f2, f3;
        if (d == 3) { f0 = f1 = f2 = f3 = 1.0f; }
        else { f0 = src[d]; f1 = src[3 + d]; f2 = src[6 + d]; f3 = src[9 + d]; }
        const h2 pa = pkrtz(f0, f1), pb = pkrtz(f2, f3);
        const h4 out4 = {pa[0], pa[1], pb[0], pb[1]};
        __fp16* dst = (__fp16*)(ws + (ismv ? WS_MVT : WS_VT))
                    + (size_t)(ismv ? (s * 16 + kt) : (s * 64 + kt)) * 256
                    + d * 64 + (4 * ((c >> 2) ^ d) + (c & 3)) * 4;
        *(h4*)dst = out4;
    }
}

// -------- Main: r11 structure + branchless, mt-interleaved softmax --------
__global__ __launch_bounds__(512) void kast_attn_kernel(
    const float* __restrict__ K,   // (2,8,4096,64) for Q
    const char* __restrict__ ws,
    float* __restrict__ OUT)       // (2,7,4096,3)
{
    __shared__ alignas(16) __fp16 sK2[2][2][64][64];   // [half][buf]
    __shared__ alignas(16) __fp16 sVT2[2][2][4][64];   // [half][buf]
    __shared__ float mrg[8][32][5];                    // [wave][q32][{m,O0,O1,O2,l}]

    const int id = blockIdx.x;
    const int sw = (id & 7) * 112 + (id >> 3);   // XCD-chunked, bijective (896%8==0)
    const int bt = sw >> 6;
    const int qblk = sw & 63;
    const int b = bt / 7, t = bt - b * 7;

    const int tid = threadIdx.x;
    const int lane = tid & 63;
    const int w = tid >> 6;      // wave 0..7
    const int h = w >> 2;        // key-half 0/1
    const int wl = w & 3;        // wave within half
    const int qsub = wl >> 1;    // query 32-subset 0/1
    const int ntp = wl & 1;      // nt-pair subset 0/1 (keys [ntp*32, ntp*32+32))
    const int col = lane & 15;   // q within M-tile
    const int g = lane >> 4;     // k-chunk group
    const int cs = col & 7;      // K-read swizzle key
    const int d3 = col & 3;      // V^T row

    // ---- Q fragments (B operand), 2 M-tiles, scaled by log2(e) ----
    h8 aq[2][2];                 // [mt][ch]
#pragma unroll
    for (int mt = 0; mt < 2; ++mt) {
        const float* qp = K + (((size_t)b * 8 + (t + 1)) * 4096
                         + (size_t)(qblk * 64 + qsub * 32 + mt * 16 + col)) * 64;
#pragma unroll
        for (int ch = 0; ch < 2; ++ch) {
            const int cc = ch * 32 + g * 8;
            const f32x4 xa = *(const f32x4*)&qp[cc];
            const f32x4 xb = *(const f32x4*)&qp[cc + 4];
            const h2 p0 = pkrtz(xa[0] * LOG2E, xa[1] * LOG2E);
            const h2 p1 = pkrtz(xa[2] * LOG2E, xa[3] * LOG2E);
            const h2 p2 = pkrtz(xb[0] * LOG2E, xb[1] * LOG2E);
            const h2 p3 = pkrtz(xb[2] * LOG2E, xb[3] * LOG2E);
            aq[mt][ch] = (h8){p0[0], p0[1], p1[0], p1[1], p2[0], p2[1], p3[0], p3[1]};
        }
    }

    auto stage = [&](const char* kb, const char* vb, int tkt, int buf) {
        const char* ksrc = kb + (size_t)tkt * 8192 + wl * 2048 + lane * 16;
        char* kdst = ((char*)&sK2[h][buf][0][0]) + wl * 2048 + lane * 16;
        gll16(ksrc, kdst);
        gll16(ksrc + 1024, kdst + 1024);
        if (wl == 0 && lane < 32)
            ((f32x4*)&sVT2[h][buf][0][0])[lane] =
                ((const f32x4*)(vb + (size_t)tkt * 512))[lane];
    };

    float oa0 = 0.f, oa1 = 0.f, oa2 = 0.f;   // merge accumulators (tid<64)

#pragma unroll
    for (int phase = 0; phase < 2; ++phase) {
        const char* kbase; const char* vbase; int ntile; float wgt;
        if (phase == 0) {
            ntile = 32; wgt = 0.8f;
            kbase = ws + WS_K  + ((size_t)bt * 64 + h * 32) * 8192;
            vbase = ws + WS_VT + ((size_t)bt * 64 + h * 32) * 512;
        } else {
            ntile = 8; wgt = 0.2f;
            kbase = ws + WS_MK  + ((size_t)bt * 16 + h * 8) * 8192;
            vbase = ws + WS_MVT + ((size_t)bt * 16 + h * 8) * 512;
        }

        // prologue: tile 0 -> buf 0
        stage(kbase, vbase, 0, 0);
        __syncthreads();

        float mrun0 = -1e30f, mrun1 = -1e30f;
        f32x4 O[2] = {(f32x4){0.f,0.f,0.f,0.f}, (f32x4){0.f,0.f,0.f,0.f}};

        for (int kt = 0; kt < ntile; ++kt) {
            const int cur = kt & 1;

            // issue next tile's staging early; end-of-iter __syncthreads drains it
            if (kt + 1 < ntile) stage(kbase, vbase, kt + 1, cur ^ 1);

            // ---- QK^T (swapped: A=K frag, B=Q frag); this wave: 32k x 32q ----
            f32x4 acc[2][2];   // [mt][nt-local]
#pragma unroll
            for (int mt = 0; mt < 2; ++mt)
#pragma unroll
                for (int nt = 0; nt < 2; ++nt) acc[mt][nt] = (f32x4){0.f,0.f,0.f,0.f};
            __builtin_amdgcn_s_setprio(1);
#pragma unroll
            for (int ch = 0; ch < 2; ++ch) {
                h8 bh[2];
#pragma unroll
                for (int nt = 0; nt < 2; ++nt) {
                    const int nt2 = ntp * 2 + nt;
                    bh[nt] = *(const h8*)&sK2[h][cur][nt2 * 16 + col][((ch * 4 + g) ^ cs) * 8];
                }
#pragma unroll
                for (int mt = 0; mt < 2; ++mt)
#pragma unroll
                    for (int nt = 0; nt < 2; ++nt)
                        acc[mt][nt] = __builtin_amdgcn_mfma_f32_16x16x32_f16(bh[nt], aq[mt][ch], acc[mt][nt], 0, 0, 0);
            }
            __builtin_amdgcn_s_setprio(0);
            // lane holds S[key = (ntp*2+nt)*16 + 4g + j][q = qsub*32 + mt*16 + col]

            // ---- per-query softmax, BRANCHLESS, both mt interleaved ----
            {
                float tm0 = acc[0][0][0], tm1 = acc[1][0][0];
#pragma unroll
                for (int nt = 0; nt < 2; ++nt)
#pragma unroll
                    for (int j = 0; j < 4; ++j) {
                        tm0 = fmaxf(tm0, acc[0][nt][j]);
                        tm1 = fmaxf(tm1, acc[1][nt][j]);
                    }
                float s0 = __shfl_xor(tm0, 16), s1 = __shfl_xor(tm1, 16);
                tm0 = fmaxf(tm0, s0); tm1 = fmaxf(tm1, s1);
                s0 = __shfl_xor(tm0, 32); s1 = __shfl_xor(tm1, 32);
                tm0 = fmaxf(tm0, s0); tm1 = fmaxf(tm1, s1);
                const float m0 = fmaxf(mrun0, tm0), m1 = fmaxf(mrun1, tm1);
                const float sc0 = __builtin_amdgcn_exp2f(mrun0 - m0);  // ==1.0 when no new max
                const float sc1 = __builtin_amdgcn_exp2f(mrun1 - m1);
                O[0] *= sc0; O[1] *= sc1;
                mrun0 = m0; mrun1 = m1;
            }

            // ---- P = exp2(S-m) -> fp16, PV + lsum on MFMA pipe (shared V frag) ----
            const char* vtb = (const char*)&sVT2[h][cur][0][0] + d3 * 128;
#pragma unroll
            for (int nt = 0; nt < 2; ++nt) {
                const int nt2 = ntp * 2 + nt;
                const h4 vf = *(const h4*)(vtb + (4 * (nt2 ^ d3) + g) * 8);
                const float a00 = __builtin_amdgcn_exp2f(acc[0][nt][0] - mrun0);
                const float a01 = __builtin_amdgcn_exp2f(acc[0][nt][1] - mrun0);
                const float a02 = __builtin_amdgcn_exp2f(acc[0][nt][2] - mrun0);
                const float a03 = __builtin_amdgcn_exp2f(acc[0][nt][3] - mrun0);
                const float a10 = __builtin_amdgcn_exp2f(acc[1][nt][0] - mrun1);
                const float a11 = __builtin_amdgcn_exp2f(acc[1][nt][1] - mrun1);
                const float a12 = __builtin_amdgcn_exp2f(acc[1][nt][2] - mrun1);
                const float a13 = __builtin_amdgcn_exp2f(acc[1][nt][3] - mrun1);
                const h2 pa0 = pkrtz(a00, a01), pb0 = pkrtz(a02, a03);
                const h2 pa1 = pkrtz(a10, a11), pb1 = pkrtz(a12, a13);
                const h4 pf0 = (h4){pa0[0], pa0[1], pb0[0], pb0[1]};
                const h4 pf1 = (h4){pa1[0], pa1[1], pb1[0], pb1[1]};
                O[0] = __builtin_amdgcn_mfma_f32_16x16x16f16(vf, pf0, O[0], 0, 0, 0);
                O[1] = __builtin_amdgcn_mfma_f32_16x16x16f16(vf, pf1, O[1], 0, 0, 0);
            }

            __syncthreads();   // drains staged tile kt+1; safe buffer swap
        }

        // ---- partials to LDS; exact 4-way flash merge for this phase ----
        if (g == 0) {
            float* m5a = &mrg[w][col][0];
            m5a[0] = mrun0;
            m5a[1] = O[0][0]; m5a[2] = O[0][1]; m5a[3] = O[0][2]; m5a[4] = O[0][3];
            float* m5b = &mrg[w][16 + col][0];
            m5b[0] = mrun1;
            m5b[1] = O[1][0]; m5b[2] = O[1][1]; m5b[3] = O[1][2]; m5b[4] = O[1][3];
        }
        __syncthreads();
        if (tid < 64) {
            const int qh = tid >> 5, ql = tid & 31;
            // contributing waves for query qh*32+ql: w = h*4 + qh*2 + ntp
            float m = -1e30f;
#pragma unroll
            for (int c = 0; c < 4; ++c) {
                const int w4 = (c >> 1) * 4 + qh * 2 + (c & 1);
                m = fmaxf(m, mrg[w4][ql][0]);
            }
            float l = 0.f, r0 = 0.f, r1 = 0.f, r2 = 0.f;
#pragma unroll
            for (int c = 0; c < 4; ++c) {
                const int w4 = (c >> 1) * 4 + qh * 2 + (c & 1);
                const float* m5 = &mrg[w4][ql][0];
                const float e = __builtin_amdgcn_exp2f(m5[0] - m);
                r0 += m5[1] * e; r1 += m5[2] * e; r2 += m5[3] * e;
                l  += m5[4] * e;
            }
            const float inv = wgt / l;
            oa0 += r0 * inv; oa1 += r1 * inv; oa2 += r2 * inv;
        }
        // next phase's prologue barrier orders mrg reuse
    }

    if (tid < 64) {
        const int q = qblk * 64 + tid;
        float* op = OUT + (((size_t)b * 7 + t) * 4096 + (size_t)q) * 3;
        op[0] = oa0; op[1] = oa1; op[2] = oa2;
    }
}

// ---------------- Fallback (round-4 kernel, known-good) if ws too small ----------------
__global__ __launch_bounds__(256) void kast_attn_fb(
    const float* __restrict__ K, const float* __restrict__ V,
    const float* __restrict__ MK, const float* __restrict__ MV,
    float* __restrict__ OUT)
{
    __shared__ alignas(16) __fp16 sK[2][64][64];
    __shared__ alignas(16) __fp16 sVT[2][4][68];

    const int id = blockIdx.x;
    const int sw = (id & 7) * 112 + (id >> 3);
    const int bt = sw >> 6;
    const int qblk = sw & 63;
    const int b = bt / 7, t = bt % 7;

    const int tid = threadIdx.x;
    const int lane = tid & 63;
    const int w = tid >> 6;
    const int col = lane & 15;
    const int g = lane >> 4;

    const int r = tid >> 2;
    const int c0 = (tid & 3) * 16;
    const int rs = (r & 7) << 3;
    const unsigned vr = (unsigned)tid / 3u;
    const unsigned vd = (unsigned)tid - vr * 3u;

    if (tid < 128) sVT[tid >> 6][3][tid & 63] = (__fp16)1.0f;

    const float* Qbase = K + (((size_t)b * 8 + (t + 1)) * 4096) * 64;
    h8 aq[2];
    {
        const int qrow = qblk * 64 + w * 16 + col;
        const float* qp = Qbase + (size_t)qrow * 64;
#pragma unroll
        for (int ch = 0; ch < 2; ++ch) {
            const int cc = ch * 32 + g * 8;
            const f32x4 xa = *(const f32x4*)&qp[cc];
            const f32x4 xb = *(const f32x4*)&qp[cc + 4];
            const h2 p0 = pkrtz(xa[0] * LOG2E, xa[1] * LOG2E);
            const h2 p1 = pkrtz(xa[2] * LOG2E, xa[3] * LOG2E);
            const h2 p2 = pkrtz(xb[0] * LOG2E, xb[1] * LOG2E);
            const h2 p3 = pkrtz(xb[2] * LOG2E, xb[3] * LOG2E);
            aq[ch] = (h8){p0[0], p0[1], p1[0], p1[1], p2[0], p2[1], p3[0], p3[1]};
        }
    }

    float outc0 = 0.f, outc1 = 0.f, outc2 = 0.f;

    for (int phase = 0; phase < 2; ++phase) {
        const float* kp; const float* vp; int ntile; float wgt;
        if (phase == 0) {
            kp = K + (((size_t)b * 8 + t) * 4096) * 64;
            vp = V + (((size_t)b * 8 + t) * 4096) * 3;
            ntile = 64; wgt = 0.8f;
        } else {
            kp = MK + (((size_t)b * 7 + t) * 1024) * 64;
            vp = MV + (((size_t)b * 7 + t) * 1024) * 3;
            ntile = 16; wgt = 0.2f;
        }
        {
            const float* src = kp + ((size_t)r) * 64 + c0;
            const f32x4* s4 = (const f32x4*)src;
            const f32x4 ra = s4[0], rb = s4[1], rc = s4[2], rd = s4[3];
            const h2 q0 = pkrtz(ra[0], ra[1]), q1 = pkrtz(ra[2], ra[3]);
            const h2 q2 = pkrtz(rb[0], rb[1]), q3 = pkrtz(rb[2], rb[3]);
            const h2 q4 = pkrtz(rc[0], rc[1]), q5 = pkrtz(rc[2], rc[3]);
            const h2 q6 = pkrtz(rd[0], rd[1]), q7 = pkrtz(rd[2], rd[3]);
            *(h8*)&sK[0][r][c0 ^ rs] = (h8){q0[0], q0[1], q1[0], q1[1], q2[0], q2[1], q3[0], q3[1]};
            *(h8*)&sK[0][r][(c0 + 8) ^ rs] = (h8){q4[0], q4[1], q5[0], q5[1], q6[0], q6[1], q7[0], q7[1]};
            if (tid < 192) sVT[0][vd][vr] = (__fp16)vp[tid];
        }
        __syncthreads();

        float mrun = -1e30f;
        f32x4 O = (f32x4){0.f, 0.f, 0.f, 0.f};

        for (int kt = 0; kt < ntile; ++kt) {
            const int cur = kt & 1;
            const bool have = (kt + 1) < ntile;
            f32x4 ra, rb, rc, rd; float rv = 0.f;
            if (have) {
                const float* src = kp + ((size_t)(kt + 1) * 64 + r) * 64 + c0;
                const f32x4* s4 = (const f32x4*)src;
                ra = s4[0]; rb = s4[1]; rc = s4[2]; rd = s4[3];
                if (tid < 192) rv = vp[(size_t)(kt + 1) * 192 + tid];
            }
            f32x4 acc[4];
#pragma unroll
            for (int nt = 0; nt < 4; ++nt) acc[nt] = (f32x4){0.f, 0.f, 0.f, 0.f};
#pragma unroll
            for (int ch = 0; ch < 2; ++ch) {
                h8 bh[4];
#pragma unroll
                for (int nt = 0; nt < 4; ++nt) {
                    const int rr = nt * 16 + col;
                    const int cc = (ch * 32 + g * 8) ^ ((rr & 7) << 3);
                    bh[nt] = *(const h8*)&sK[cur][rr][cc];
                }
#pragma unroll
                for (int nt = 0; nt < 4; ++nt)
                    acc[nt] = __builtin_amdgcn_mfma_f32_16x16x32_f16(bh[nt], aq[ch], acc[nt], 0, 0, 0);
            }
            {
                float tm = acc[0][0];
#pragma unroll
                for (int nt = 0; nt < 4; ++nt)
#pragma unroll
                    for (int j = 0; j < 4; ++j) tm = fmaxf(tm, acc[nt][j]);
                tm = fmaxf(tm, __shfl_xor(tm, 16));
                tm = fmaxf(tm, __shfl_xor(tm, 32));
                if (!__all(tm <= mrun)) {
                    const float mnew = fmaxf(mrun, tm);
                    const float sc = __builtin_amdgcn_exp2f(mrun - mnew);
                    O *= sc;
                    mrun = mnew;
                }
            }
#pragma unroll
            for (int nt = 0; nt < 4; ++nt) {
                const float p0 = __builtin_amdgcn_exp2f(acc[nt][0] - mrun);
                const float p1 = __builtin_amdgcn_exp2f(acc[nt][1] - mrun);
                const float p2 = __builtin_amdgcn_exp2f(acc[nt][2] - mrun);
                const float p3 = __builtin_amdgcn_exp2f(acc[nt][3] - mrun);
                const h2 pa = pkrtz(p0, p1), pb = pkrtz(p2, p3);
                const h4 pf = (h4){pa[0], pa[1], pb[0], pb[1]};
                const h4 vf = *(const h4*)&sVT[cur][col & 3][nt * 16 + 4 * g];
                O = __builtin_amdgcn_mfma_f32_16x16x16f16(vf, pf, O, 0, 0, 0);
            }
            if (have) {
                const int nb = cur ^ 1;
                const h2 q0 = pkrtz(ra[0], ra[1]), q1 = pkrtz(ra[2], ra[3]);
                const h2 q2 = pkrtz(rb[0], rb[1]), q3 = pkrtz(rb[2], rb[3]);
                const h2 q4 = pkrtz(rc[0], rc[1]), q5 = pkrtz(rc[2], rc[3]);
                const h2 q6 = pkrtz(rd[0], rd[1]), q7 = pkrtz(rd[2], rd[3]);
                *(h8*)&sK[nb][r][c0 ^ rs] = (h8){q0[0], q0[1], q1[0], q1[1], q2[0], q2[1], q3[0], q3[1]};
                *(h8*)&sK[nb][r][(c0 + 8) ^ rs] = (h8){q4[0], q4[1], q5[0], q5[1], q6[0], q6[1], q7[0], q7[1]};
                if (tid < 192) sVT[nb][vd][vr] = (__fp16)rv;
            }
            __syncthreads();
        }
        const float inv = wgt / O[3];
        outc0 += O[0] * inv;
        outc1 += O[1] * inv;
        outc2 += O[2] * inv;
    }

    if (g == 0) {
        const int q = qblk * 64 + w * 16 + col;
        float* op = OUT + (((size_t)b * 7 + t) * 4096 + (size_t)q) * 3;
        op[0] = outc0; op[1] = outc1; op[2] = outc2;
    }
}

extern "C" void kernel_launch(void* const* d_in, const int* in_sizes, int n_in,
                              void* d_out, int out_size, void* d_ws, size_t ws_size,
                              hipStream_t stream) {
    const float* K  = (const float*)d_in[0];
    const float* V  = (const float*)d_in[1];
    const float* MK = (const float*)d_in[2];
    const float* MV = (const float*)d_in[3];
    float* OUT = (float*)d_out;
    if (ws_size >= WS_NEED) {
        hipLaunchKernelGGL(kast_pre_kernel, dim3(2520), dim3(256), 0, stream,
                           K, V, MK, MV, (char*)d_ws);
        hipLaunchKernelGGL(kast_attn_kernel, dim3(896), dim3(512), 0, stream,
                           K, (const char*)d_ws, OUT);
    } else {
        hipLaunchKernelGGL(kast_attn_fb, dim3(896), dim3(256), 0, stream,
                           K, V, MK, MV, OUT);
    }
}